// Round 2
// baseline (1122.306 us; speedup 1.0000x reference)
//
#include <hip/hip_runtime.h>
#include <math.h>

#define NB 16
#define SS 2048
#define DQ 128
#define SCALE 0.08838834764831845f  // 1/sqrt(128)

// ---------------------------------------------------------------------------
// Pass 1: colsum[b][k] = sum_q exp(masked_score[b][q][k]); writes 1/colsum
// REPLICATED into every pass-2 block's output territory in d_out:
//   flat offset (b*SS + q0)*DQ + k   for each q0 in {0,64,...,SS-64}
// (no d_ws dependence — ws_size is unknown; R0 failed on OOB ws writes)
// grid (SS/128, NB), block 256.  128k x 128q tiles, 8x8 micro-tile/thread.
// ---------------------------------------------------------------------------
__global__ __launch_bounds__(256) void pass1_colsum(
    const float* __restrict__ Q, const float* __restrict__ K,
    const int* __restrict__ M, float* __restrict__ O)
{
  const int b   = blockIdx.y;
  const int k0  = blockIdx.x * 128;
  const int tid = threadIdx.x;
  const int tx  = tid & 15;   // k-group (8 wide)
  const int ty  = tid >> 4;   // q-group (8 wide)

  __shared__ __align__(16) float Qs[32][132];   // [d][q], padded
  __shared__ __align__(16) float Ks[32][132];   // [d][k], padded
  __shared__ __align__(16) float red[16][128];

  const float* Qb = Q + (size_t)b * SS * DQ;
  const float* Kb = K + (size_t)b * SS * DQ;
  const int*   Mb = M + (size_t)b * SS * SS;

  float colacc[8];
#pragma unroll
  for (int j = 0; j < 8; ++j) colacc[j] = 0.f;

  for (int q0 = 0; q0 < SS; q0 += 128) {
    float c[8][8];
#pragma unroll
    for (int i = 0; i < 8; ++i)
#pragma unroll
      for (int j = 0; j < 8; ++j) c[i][j] = 0.f;

    for (int dc = 0; dc < DQ; dc += 32) {
      __syncthreads();
#pragma unroll
      for (int r = 0; r < 4; ++r) {
        int e   = tid + r * 256;        // 0..1023
        int row = e >> 3;               // 0..127
        int c4  = (e & 7) << 2;         // 0..28
        float4 v = *(const float4*)(Qb + (size_t)(q0 + row) * DQ + dc + c4);
        Qs[c4+0][row] = v.x; Qs[c4+1][row] = v.y;
        Qs[c4+2][row] = v.z; Qs[c4+3][row] = v.w;
        float4 w = *(const float4*)(Kb + (size_t)(k0 + row) * DQ + dc + c4);
        Ks[c4+0][row] = w.x; Ks[c4+1][row] = w.y;
        Ks[c4+2][row] = w.z; Ks[c4+3][row] = w.w;
      }
      __syncthreads();
#pragma unroll 8
      for (int d = 0; d < 32; ++d) {
        float qr[8], kr[8];
        *(float4*)&qr[0] = *(const float4*)&Qs[d][ty*8];
        *(float4*)&qr[4] = *(const float4*)&Qs[d][ty*8 + 4];
        *(float4*)&kr[0] = *(const float4*)&Ks[d][tx*8];
        *(float4*)&kr[4] = *(const float4*)&Ks[d][tx*8 + 4];
#pragma unroll
        for (int i = 0; i < 8; ++i)
#pragma unroll
          for (int j = 0; j < 8; ++j)
            c[i][j] = fmaf(qr[i], kr[j], c[i][j]);
      }
    }
    // mask + exp + column accumulate
#pragma unroll
    for (int i = 0; i < 8; ++i) {
      const int q = q0 + ty*8 + i;
      const int* mrow = Mb + (size_t)q * SS + k0 + tx*8;
      int4 m0 = *(const int4*)(mrow);
      int4 m1 = *(const int4*)(mrow + 4);
      int mm[8] = {m0.x, m0.y, m0.z, m0.w, m1.x, m1.y, m1.z, m1.w};
#pragma unroll
      for (int j = 0; j < 8; ++j) {
        float s = mm[j] ? 1e-9f : c[i][j] * SCALE;
        colacc[j] += __expf(s);
      }
    }
  }

  __syncthreads();
#pragma unroll
  for (int j = 0; j < 8; ++j) red[ty][tx*8 + j] = colacc[j];
  __syncthreads();
  if (tid < 128) {
    float s = 0.f;
#pragma unroll
    for (int t = 0; t < 16; ++t) s += red[t][tid];
    const float inv = 1.0f / s;
    // replicate Linv into every pass-2 block territory (rows q0..q0+15)
    for (int q0 = 0; q0 < SS; q0 += 64) {
      O[((size_t)b * SS + q0) * DQ + k0 + tid] = inv;
    }
  }
}

// ---------------------------------------------------------------------------
// Pass 2: O[b][q][d] = sum_k exp(masked_score) * Linv[k] * V[k][d]
// grid (SS/64, NB), block 256.  64q tile; stream 64k tiles.
// First copies its territory's replicated Linv strip (2048 floats) into LDS,
// then overwrites the territory at the end. QK micro 4x4; PV micro 4q x 8d.
// ---------------------------------------------------------------------------
__global__ __launch_bounds__(256) void pass2_out(
    const float* __restrict__ Q, const float* __restrict__ K,
    const float* __restrict__ V, const int* __restrict__ M,
    float* __restrict__ O)
{
  const int b   = blockIdx.y;
  const int q0  = blockIdx.x * 64;
  const int tid = threadIdx.x;
  const int tx  = tid & 15;
  const int ty  = tid >> 4;

  __shared__ __align__(16) float Qs[32][68];    // [d][q]
  __shared__ __align__(16) float Ks[32][68];    // [d][k]
  __shared__ __align__(16) float Es[64][68];    // [k][q]  exp-scores, transposed
  __shared__ __align__(16) float Vs[64][132];   // [k][d]  V * Linv
  __shared__ __align__(16) float Li[SS];        // 1/colsum, all 2048 k

  const float* Qb = Q + (size_t)b * SS * DQ;
  const float* Kb = K + (size_t)b * SS * DQ;
  const float* Vb = V + (size_t)b * SS * DQ;
  const int*   Mb = M + (size_t)b * SS * SS;

  // ---- preload this block's replicated Linv strip (contiguous 2048 floats)
  {
    const float* src = O + ((size_t)b * SS + q0) * DQ;
#pragma unroll
    for (int r = 0; r < 2; ++r) {
      int idx = (tid + r * 256) * 4;   // 0..2044
      *(float4*)&Li[idx] = *(const float4*)(src + idx);
    }
  }
  // (first read of Li is after several __syncthreads in the dc loop — ordered)

  float o[4][8];
#pragma unroll
  for (int i = 0; i < 4; ++i)
#pragma unroll
    for (int j = 0; j < 8; ++j) o[i][j] = 0.f;

  for (int k0 = 0; k0 < SS; k0 += 64) {
    float c[4][4];
#pragma unroll
    for (int i = 0; i < 4; ++i)
#pragma unroll
      for (int j = 0; j < 4; ++j) c[i][j] = 0.f;

    for (int dc = 0; dc < DQ; dc += 32) {
      __syncthreads();   // also guards Es/Vs against previous PV readers
#pragma unroll
      for (int r = 0; r < 2; ++r) {
        int e   = tid + r * 256;   // 0..511
        int row = e >> 3;          // 0..63
        int c4  = (e & 7) << 2;
        float4 v = *(const float4*)(Qb + (size_t)(q0 + row) * DQ + dc + c4);
        Qs[c4+0][row] = v.x; Qs[c4+1][row] = v.y;
        Qs[c4+2][row] = v.z; Qs[c4+3][row] = v.w;
        float4 w = *(const float4*)(Kb + (size_t)(k0 + row) * DQ + dc + c4);
        Ks[c4+0][row] = w.x; Ks[c4+1][row] = w.y;
        Ks[c4+2][row] = w.z; Ks[c4+3][row] = w.w;
      }
      __syncthreads();
#pragma unroll 8
      for (int d = 0; d < 32; ++d) {
        float4 qv = *(const float4*)&Qs[d][ty*4];
        float4 kv = *(const float4*)&Ks[d][tx*4];
        float qr[4] = {qv.x, qv.y, qv.z, qv.w};
        float kr[4] = {kv.x, kv.y, kv.z, kv.w};
#pragma unroll
        for (int i = 0; i < 4; ++i)
#pragma unroll
          for (int j = 0; j < 4; ++j)
            c[i][j] = fmaf(qr[i], kr[j], c[i][j]);
      }
    }

    // mask + exp -> Es (transposed [k][q])
    float ee[4][4];
#pragma unroll
    for (int i = 0; i < 4; ++i) {
      const int q = q0 + ty*4 + i;
      int4 m = *(const int4*)(Mb + (size_t)q * SS + k0 + tx*4);
      int mm[4] = {m.x, m.y, m.z, m.w};
#pragma unroll
      for (int j = 0; j < 4; ++j)
        ee[i][j] = __expf(mm[j] ? 1e-9f : c[i][j] * SCALE);
    }
#pragma unroll
    for (int j = 0; j < 4; ++j) {
      float4 ev = make_float4(ee[0][j], ee[1][j], ee[2][j], ee[3][j]);
      *(float4*)&Es[tx*4 + j][ty*4] = ev;
    }

    // stage Vs = V * Linv (Linv from LDS)
#pragma unroll
    for (int r = 0; r < 8; ++r) {
      int e   = tid + r * 256;    // 0..2047
      int row = e >> 5;           // 0..63
      int c4  = (e & 31) << 2;    // 0..124
      float li = Li[k0 + row];
      float4 v = *(const float4*)(Vb + (size_t)(k0 + row) * DQ + c4);
      v.x *= li; v.y *= li; v.z *= li; v.w *= li;
      *(float4*)&Vs[row][c4] = v;
    }
    __syncthreads();

    // PV accumulate: o[4q][8d] += Es[kk][q] * Vs[kk][d]
#pragma unroll 8
    for (int kk = 0; kk < 64; ++kk) {
      float4 eq = *(const float4*)&Es[kk][ty*4];
      float4 v0 = *(const float4*)&Vs[kk][tx*8];
      float4 v1 = *(const float4*)&Vs[kk][tx*8 + 4];
      float er[4] = {eq.x, eq.y, eq.z, eq.w};
      float vr[8] = {v0.x, v0.y, v0.z, v0.w, v1.x, v1.y, v1.z, v1.w};
#pragma unroll
      for (int i = 0; i < 4; ++i)
#pragma unroll
        for (int j = 0; j < 8; ++j)
          o[i][j] = fmaf(er[i], vr[j], o[i][j]);
    }
  }

  // write output (overwrites the Linv strip — all reads of it are long done)
#pragma unroll
  for (int i = 0; i < 4; ++i) {
    const int q = q0 + ty*4 + i;
    float* op = O + ((size_t)b * SS + q) * DQ + tx*8;
    *(float4*)(op)     = make_float4(o[i][0], o[i][1], o[i][2], o[i][3]);
    *(float4*)(op + 4) = make_float4(o[i][4], o[i][5], o[i][6], o[i][7]);
  }
}

// ---------------------------------------------------------------------------
extern "C" void kernel_launch(void* const* d_in, const int* in_sizes, int n_in,
                              void* d_out, int out_size, void* d_ws, size_t ws_size,
                              hipStream_t stream) {
  const float* Q = (const float*)d_in[0];
  const float* K = (const float*)d_in[1];
  const float* V = (const float*)d_in[2];
  const int*   M = (const int*)d_in[3];
  float* O = (float*)d_out;
  (void)d_ws; (void)ws_size;   // d_ws unused: ws_size unverified (R0 post-mortem)

  dim3 blk(256);
  dim3 g1(SS / 128, NB);
  pass1_colsum<<<g1, blk, 0, stream>>>(Q, K, M, O);
  dim3 g2(SS / 64, NB);
  pass2_out<<<g2, blk, 0, stream>>>(Q, K, V, M, O);
}

// Round 3
// 964.248 us; speedup vs baseline: 1.1639x; 1.1639x over previous
//
#include <hip/hip_runtime.h>
#include <math.h>

#define NB 16
#define SS 2048
#define DQ 128
#define SCALE 0.08838834764831845f  // 1/sqrt(128)

typedef __bf16 bf16x8 __attribute__((ext_vector_type(8)));
typedef unsigned short ushort8_t __attribute__((ext_vector_type(8)));
typedef float floatx4 __attribute__((ext_vector_type(4)));

// fp32 -> bf16 round-to-nearest-even (inputs are finite randn; no NaN path)
__device__ __forceinline__ unsigned short f2bf(float x) {
  unsigned int u = __float_as_uint(x);
  u += 0x7fffu + ((u >> 16) & 1u);
  return (unsigned short)(u >> 16);
}

union FragU { ushort8_t u; bf16x8 b; };

__device__ __forceinline__ bf16x8 ld_frag(const unsigned short* p) {
  FragU t; t.u = *(const ushort8_t*)p; return t.b;
}

__device__ __forceinline__ floatx4 mfma16(bf16x8 a, bf16x8 b, floatx4 c) {
  return __builtin_amdgcn_mfma_f32_16x16x32_bf16(a, b, c, 0, 0, 0);
}

// ---------------------------------------------------------------------------
// Pass 1: Linv[b][k] = 1/sum_q exp(masked_score), written replicated into
// each pass-2 block's d_out territory (same scheme as R1 — verified).
// grid (SS/128, NB), 256 thr = 4 waves. Block tile 128k x 128q per q-iter.
// Wave quadrants 64x64, 4x4 grid of 16x16x32 bf16 MFMAs.
// ---------------------------------------------------------------------------
__global__ __launch_bounds__(256, 2) void pass1_colsum(
    const float* __restrict__ Q, const float* __restrict__ K,
    const int* __restrict__ M, float* __restrict__ O)
{
  const int b    = blockIdx.y;
  const int k0   = blockIdx.x * 128;
  const int tid  = threadIdx.x;
  const int w    = tid >> 6;
  const int lane = tid & 63;
  const int l15  = lane & 15;
  const int quad = lane >> 4;
  const int mq   = (w & 1) * 64;   // q-quadrant
  const int nq   = (w >> 1) * 64;  // k-quadrant

  __shared__ unsigned short Kbf[128][136];  // 34.8 KB, resident
  __shared__ unsigned short Qbf[128][136];  // 34.8 KB, per q-iter
  __shared__ float red[4][64];

  const float* Qb = Q + (size_t)b * SS * DQ;
  const float* Kb = K + (size_t)b * SS * DQ;
  const int*   Mb = M + (size_t)b * SS * SS;

  // stage K strip: 128 rows x 128 d -> bf16
#pragma unroll
  for (int r = 0; r < 16; ++r) {
    int idx = tid + r * 256;       // 0..4095 float4s
    int row = idx >> 5;
    int c4  = (idx & 31) * 4;
    float4 v = *(const float4*)(Kb + (size_t)(k0 + row) * DQ + c4);
    *(ushort4*)&Kbf[row][c4] = make_ushort4(f2bf(v.x), f2bf(v.y), f2bf(v.z), f2bf(v.w));
  }

  float colacc[4] = {0.f, 0.f, 0.f, 0.f};

  for (int q0 = 0; q0 < SS; q0 += 128) {
    __syncthreads();   // Qbf free (and first iter: Kbf staged)
#pragma unroll
    for (int r = 0; r < 16; ++r) {
      int idx = tid + r * 256;
      int row = idx >> 5;
      int c4  = (idx & 31) * 4;
      float4 v = *(const float4*)(Qb + (size_t)(q0 + row) * DQ + c4);
      *(ushort4*)&Qbf[row][c4] = make_ushort4(f2bf(v.x), f2bf(v.y), f2bf(v.z), f2bf(v.w));
    }
    __syncthreads();

    floatx4 acc[4][4];
#pragma unroll
    for (int i = 0; i < 4; ++i)
#pragma unroll
      for (int j = 0; j < 4; ++j) acc[i][j] = (floatx4){0.f, 0.f, 0.f, 0.f};

#pragma unroll
    for (int d0 = 0; d0 < DQ; d0 += 32) {
      bf16x8 a[4], bb[4];
#pragma unroll
      for (int i = 0; i < 4; ++i) a[i]  = ld_frag(&Qbf[mq + 16 * i + l15][d0 + quad * 8]);
#pragma unroll
      for (int j = 0; j < 4; ++j) bb[j] = ld_frag(&Kbf[nq + 16 * j + l15][d0 + quad * 8]);
#pragma unroll
      for (int i = 0; i < 4; ++i)
#pragma unroll
        for (int j = 0; j < 4; ++j)
          acc[i][j] = mfma16(a[i], bb[j], acc[i][j]);
    }

    // epilogue: mask + exp + column accumulate
    // C/D layout: col = lane&15 (k), row = quad*4 + reg (q)
#pragma unroll
    for (int i = 0; i < 4; ++i) {
      const int q = q0 + mq + 16 * i + quad * 4;
#pragma unroll
      for (int j = 0; j < 4; ++j) {
        const int k = k0 + nq + 16 * j + l15;
        const int* mp = Mb + (size_t)q * SS + k;
#pragma unroll
        for (int r = 0; r < 4; ++r) {
          int m = mp[(size_t)r * SS];
          float s = m ? 1e-9f : acc[i][j][r] * SCALE;
          colacc[j] += __expf(s);
        }
      }
    }
  }

  // reduce across quads (same k lives in lanes l15, l15+16, l15+32, l15+48)
#pragma unroll
  for (int j = 0; j < 4; ++j) {
    colacc[j] += __shfl_xor(colacc[j], 16, 64);
    colacc[j] += __shfl_xor(colacc[j], 32, 64);
  }
  if (lane < 16) {
#pragma unroll
    for (int j = 0; j < 4; ++j) red[w][16 * j + l15] = colacc[j];
  }
  __syncthreads();
  if (tid < 128) {
    int k = tid;
    float s = (k < 64) ? (red[0][k] + red[1][k]) : (red[2][k - 64] + red[3][k - 64]);
    float inv = 1.0f / s;
    for (int q0 = 0; q0 < SS; q0 += 64)
      O[((size_t)b * SS + q0) * DQ + k0 + tid] = inv;
  }
}

// ---------------------------------------------------------------------------
// Pass 2: O[q][d] = sum_k exp(masked_score)*Linv[k]*V[k][d], bf16 MFMA both
// GEMMs. grid (SS/64, NB), 256 thr = 4 waves. Wave w owns q-rows [16w,16w+16).
// k-loop in tiles of 64: QK (16x16x32) -> mask+exp+Linv -> Es bf16 ->
// PV with V^T staged bf16 (B-operand layout).
// ---------------------------------------------------------------------------
__global__ __launch_bounds__(256, 2) void pass2_out(
    const float* __restrict__ Q, const float* __restrict__ K,
    const float* __restrict__ V, const int* __restrict__ M,
    float* __restrict__ O)
{
  const int b    = blockIdx.y;
  const int q0   = blockIdx.x * 64;
  const int tid  = threadIdx.x;
  const int w    = tid >> 6;
  const int lane = tid & 63;
  const int l15  = lane & 15;
  const int quad = lane >> 4;

  __shared__ unsigned short Qbf[64][136];  // 17.4 KB, resident
  __shared__ unsigned short Kbf[64][136];  // 17.4 KB, per k-iter
  __shared__ unsigned short Es[64][72];    //  9.2 KB  E' = exp*Linv, [q][k]
  __shared__ unsigned short Wt[128][72];   // 18.4 KB  V^T bf16, [d][k]
  __shared__ float Li[SS];                 //  8.0 KB

  const float* Qb = Q + (size_t)b * SS * DQ;
  const float* Kb = K + (size_t)b * SS * DQ;
  const float* Vb = V + (size_t)b * SS * DQ;
  const int*   Mb = M + (size_t)b * SS * SS;

  // preload replicated Linv strip from own territory (before any O write)
  {
    const float* src = O + ((size_t)b * SS + q0) * DQ;
#pragma unroll
    for (int r = 0; r < 2; ++r) {
      int idx = (tid + r * 256) * 4;
      *(float4*)&Li[idx] = *(const float4*)(src + idx);
    }
  }
  // stage Q tile 64x128 -> bf16 (resident)
#pragma unroll
  for (int r = 0; r < 8; ++r) {
    int idx = tid + r * 256;       // 0..2047
    int row = idx >> 5;
    int c4  = (idx & 31) * 4;
    float4 v = *(const float4*)(Qb + (size_t)(q0 + row) * DQ + c4);
    *(ushort4*)&Qbf[row][c4] = make_ushort4(f2bf(v.x), f2bf(v.y), f2bf(v.z), f2bf(v.w));
  }
  __syncthreads();

  floatx4 accO[8];
#pragma unroll
  for (int j = 0; j < 8; ++j) accO[j] = (floatx4){0.f, 0.f, 0.f, 0.f};

  for (int k0 = 0; k0 < SS; k0 += 64) {
    __syncthreads();   // Kbf/Es/Wt free from previous iteration readers
    // stage K tile 64x128 -> bf16
#pragma unroll
    for (int r = 0; r < 8; ++r) {
      int idx = tid + r * 256;
      int row = idx >> 5;
      int c4  = (idx & 31) * 4;
      float4 v = *(const float4*)(Kb + (size_t)(k0 + row) * DQ + c4);
      *(ushort4*)&Kbf[row][c4] = make_ushort4(f2bf(v.x), f2bf(v.y), f2bf(v.z), f2bf(v.w));
    }
    // stage V^T tile: read V[k][d] coalesced, write Wt[d][k] bf16
#pragma unroll
    for (int r = 0; r < 8; ++r) {
      int idx = tid + r * 256;
      int row = idx >> 5;          // k-offset 0..63
      int c4  = (idx & 31) * 4;    // d-offset
      float4 v = *(const float4*)(Vb + (size_t)(k0 + row) * DQ + c4);
      Wt[c4 + 0][row] = f2bf(v.x);
      Wt[c4 + 1][row] = f2bf(v.y);
      Wt[c4 + 2][row] = f2bf(v.z);
      Wt[c4 + 3][row] = f2bf(v.w);
    }
    __syncthreads();

    // QK: wave w -> E rows [16w, 16w+16) x 64 k
    floatx4 acc[4];
#pragma unroll
    for (int j = 0; j < 4; ++j) acc[j] = (floatx4){0.f, 0.f, 0.f, 0.f};
#pragma unroll
    for (int d0 = 0; d0 < DQ; d0 += 32) {
      bf16x8 a = ld_frag(&Qbf[16 * w + l15][d0 + quad * 8]);
#pragma unroll
      for (int j = 0; j < 4; ++j) {
        bf16x8 bb = ld_frag(&Kbf[16 * j + l15][d0 + quad * 8]);
        acc[j] = mfma16(a, bb, acc[j]);
      }
    }
    // epilogue: mask + exp, fold Linv, store Es (A-operand source layout)
#pragma unroll
    for (int j = 0; j < 4; ++j) {
      const int kk = 16 * j + l15;
      const int q  = q0 + 16 * w + quad * 4;
      const int* mp = Mb + (size_t)q * SS + k0 + kk;
      const float li = Li[k0 + kk];
#pragma unroll
      for (int r = 0; r < 4; ++r) {
        int m = mp[(size_t)r * SS];
        float s = m ? 1e-9f : acc[j][r] * SCALE;
        Es[16 * w + quad * 4 + r][kk] = f2bf(__expf(s) * li);
      }
    }
    __syncthreads();

    // PV: accO[j] += Es(A: [q][kk]) x Wt(B: [d][kk])
#pragma unroll
    for (int c = 0; c < 2; ++c) {
      bf16x8 ea = ld_frag(&Es[16 * w + l15][32 * c + quad * 8]);
#pragma unroll
      for (int j = 0; j < 8; ++j) {
        bf16x8 wb = ld_frag(&Wt[16 * j + l15][32 * c + quad * 8]);
        accO[j] = mfma16(ea, wb, accO[j]);
      }
    }
  }

  // write O: C/D layout col = lane&15 (d within tile j), row = quad*4+r (q)
#pragma unroll
  for (int j = 0; j < 8; ++j) {
#pragma unroll
    for (int r = 0; r < 4; ++r) {
      O[((size_t)b * SS + q0 + 16 * w + quad * 4 + r) * DQ + 16 * j + l15] = accO[j][r];
    }
  }
}

// ---------------------------------------------------------------------------
extern "C" void kernel_launch(void* const* d_in, const int* in_sizes, int n_in,
                              void* d_out, int out_size, void* d_ws, size_t ws_size,
                              hipStream_t stream) {
  const float* Q = (const float*)d_in[0];
  const float* K = (const float*)d_in[1];
  const float* V = (const float*)d_in[2];
  const int*   M = (const int*)d_in[3];
  float* O = (float*)d_out;
  (void)d_ws; (void)ws_size;   // d_ws unused: ws_size unverified (R0 post-mortem)

  dim3 blk(256);
  dim3 g1(SS / 128, NB);
  pass1_colsum<<<g1, blk, 0, stream>>>(Q, K, M, O);
  dim3 g2(SS / 64, NB);
  pass2_out<<<g2, blk, 0, stream>>>(Q, K, V, M, O);
}

// Round 4
// 593.804 us; speedup vs baseline: 1.8900x; 1.6238x over previous
//
#include <hip/hip_runtime.h>
#include <math.h>

#define NB 16
#define SS 2048
#define DQ 128
#define SCALE 0.08838834764831845f  // 1/sqrt(128)

typedef __bf16 bf16x8 __attribute__((ext_vector_type(8)));
typedef unsigned short ushort8_t __attribute__((ext_vector_type(8)));
typedef float floatx4 __attribute__((ext_vector_type(4)));

// fp32 -> bf16 round-to-nearest-even (finite randn inputs; no NaN path)
__device__ __forceinline__ unsigned short f2bf(float x) {
  unsigned int u = __float_as_uint(x);
  u += 0x7fffu + ((u >> 16) & 1u);
  return (unsigned short)(u >> 16);
}
union FragU { ushort8_t u; bf16x8 b; };
__device__ __forceinline__ bf16x8 ld_frag(const unsigned short* p) {
  FragU t; t.u = *(const ushort8_t*)p; return t.b;
}
__device__ __forceinline__ floatx4 mfma16(bf16x8 a, bf16x8 b, floatx4 c) {
  return __builtin_amdgcn_mfma_f32_16x16x32_bf16(a, b, c, 0, 0, 0);
}

// d_out scratch layout per batch b (each row = DQ floats):
//   rows q0..q0+15 for q0 in {0,64,...}: replicated Linv strips (2048 floats each)
//   rows 16..31: colsum accumulator (2048 floats)  [disjoint from strips]
// All overwritten by pass2's final output.

// ---------------------------------------------------------------------------
__global__ void zero_accum(float* __restrict__ O) {
  float* p = O + (size_t)blockIdx.x * SS * DQ + 16 * DQ;
#pragma unroll
  for (int i = 0; i < 8; ++i) p[threadIdx.x + 256 * i] = 0.f;
}

// ---------------------------------------------------------------------------
// Pass 1: partial colsum[b][k] += sum_{q in chunk} exp(masked_score)
// grid (32 ktiles, NB, 4 qchunks) = 2048 blocks, 256 thr, 3 blocks/CU.
// A=K (64 k), B=Q (128 q): C rows = k -> int4 mask loads, prefetched.
// ---------------------------------------------------------------------------
__global__ __launch_bounds__(256, 3) void pass1_colsum(
    const float* __restrict__ Q, const float* __restrict__ K,
    const int* __restrict__ M, float* __restrict__ O)
{
  const int k0  = blockIdx.x * 64;
  const int b   = blockIdx.y;
  const int qc  = blockIdx.z;
  const int tid = threadIdx.x;
  const int w = tid >> 6, lane = tid & 63, l15 = lane & 15, quad = lane >> 4;

  __shared__ unsigned short Kbf[64][136];    // 17.4 KB (272B rows: 16B-aligned, 2-way)
  __shared__ unsigned short Qbf[128][136];   // 34.8 KB
  __shared__ float red[4][64];

  const float* Qb = Q + (size_t)b * SS * DQ;
  const float* Kb = K + (size_t)b * SS * DQ;
  const int*   Mb = M + (size_t)b * SS * SS;

  // stage K strip 64 x 128 -> bf16 (resident)
#pragma unroll
  for (int r = 0; r < 8; ++r) {
    int idx = tid + r * 256;
    int row = idx >> 5, c4 = (idx & 31) * 4;
    float4 v = *(const float4*)(Kb + (size_t)(k0 + row) * DQ + c4);
    *(ushort4*)&Kbf[row][c4] = make_ushort4(f2bf(v.x), f2bf(v.y), f2bf(v.z), f2bf(v.w));
  }

  float colacc[16];
#pragma unroll
  for (int t = 0; t < 16; ++t) colacc[t] = 0.f;

  for (int qi = 0; qi < 4; ++qi) {
    const int q0 = qc * 512 + qi * 128;
    // prefetch mask (int4, contiguous k) BEFORE staging -> latency hidden
    int4 mv[4][2];
#pragma unroll
    for (int i = 0; i < 4; ++i)
#pragma unroll
      for (int j = 0; j < 2; ++j)
        mv[i][j] = *(const int4*)(Mb + (size_t)(q0 + 32 * w + 16 * j + l15) * SS
                                  + k0 + 16 * i + quad * 4);
    __syncthreads();  // Qbf free (first iter also covers Kbf staging)
#pragma unroll
    for (int r = 0; r < 16; ++r) {
      int idx = tid + r * 256;
      int row = idx >> 5, c4 = (idx & 31) * 4;
      float4 v = *(const float4*)(Qb + (size_t)(q0 + row) * DQ + c4);
      *(ushort4*)&Qbf[row][c4] = make_ushort4(f2bf(v.x), f2bf(v.y), f2bf(v.z), f2bf(v.w));
    }
    __syncthreads();

    floatx4 acc[4][2];
#pragma unroll
    for (int i = 0; i < 4; ++i)
#pragma unroll
      for (int j = 0; j < 2; ++j) acc[i][j] = (floatx4){0.f, 0.f, 0.f, 0.f};

#pragma unroll
    for (int d0 = 0; d0 < DQ; d0 += 32) {
      bf16x8 a[4], bb[2];
#pragma unroll
      for (int i = 0; i < 4; ++i) a[i] = ld_frag(&Kbf[16 * i + l15][d0 + quad * 8]);
#pragma unroll
      for (int j = 0; j < 2; ++j) bb[j] = ld_frag(&Qbf[32 * w + 16 * j + l15][d0 + quad * 8]);
#pragma unroll
      for (int i = 0; i < 4; ++i)
#pragma unroll
        for (int j = 0; j < 2; ++j)
          acc[i][j] = mfma16(a[i], bb[j], acc[i][j]);
    }
    // epilogue: C row = k_local = 16i+quad*4+r, col = q = 32w+16j+l15
#pragma unroll
    for (int i = 0; i < 4; ++i)
#pragma unroll
      for (int j = 0; j < 2; ++j) {
        int mm[4] = {mv[i][j].x, mv[i][j].y, mv[i][j].z, mv[i][j].w};
#pragma unroll
        for (int r = 0; r < 4; ++r) {
          float s = mm[r] ? 1e-9f : acc[i][j][r] * SCALE;
          colacc[i * 4 + r] += __expf(s);
        }
      }
  }

  // reduce over the 16 q-lanes (l15 dimension)
#pragma unroll
  for (int t = 0; t < 16; ++t) {
    colacc[t] += __shfl_xor(colacc[t], 1, 64);
    colacc[t] += __shfl_xor(colacc[t], 2, 64);
    colacc[t] += __shfl_xor(colacc[t], 4, 64);
    colacc[t] += __shfl_xor(colacc[t], 8, 64);
  }
  if (l15 == 0) {
#pragma unroll
    for (int i = 0; i < 4; ++i)
#pragma unroll
      for (int r = 0; r < 4; ++r)
        red[w][16 * i + quad * 4 + r] = colacc[i * 4 + r];
  }
  __syncthreads();
  if (tid < 64) {
    float s = red[0][tid] + red[1][tid] + red[2][tid] + red[3][tid];
    atomicAdd(O + (size_t)b * SS * DQ + 16 * DQ + k0 + tid, s);
  }
}

// ---------------------------------------------------------------------------
// Combine: inv = 1/colsum; write replicated strips. grid (NB, 8), 256 thr.
// ---------------------------------------------------------------------------
__global__ void combine_linv(float* __restrict__ O) {
  const int b  = blockIdx.x;
  const int jb = blockIdx.y * 4;
  float* Ob = O + (size_t)b * SS * DQ;
#pragma unroll
  for (int it = 0; it < 8; ++it) {
    int k = threadIdx.x + 256 * it;
    float inv = 1.0f / Ob[16 * DQ + k];
#pragma unroll
    for (int j = 0; j < 4; ++j)
      Ob[(size_t)(64 * (jb + j)) * DQ + k] = inv;
  }
}

// ---------------------------------------------------------------------------
// Pass 2: O[q][d] = sum_k exp(masked_score)*Linv[k]*V[k][d]
// grid (32, NB), 256 thr, 2 blocks/CU. A=K,B=Q for QK (int4 mask, prefetched);
// A=Wt(V^T, xor-swizzled), B=Es for PV -> float4 output stores.
// ---------------------------------------------------------------------------
__global__ __launch_bounds__(256, 2) void pass2_out(
    const float* __restrict__ Q, const float* __restrict__ K,
    const float* __restrict__ V, const int* __restrict__ M,
    float* __restrict__ O)
{
  const int b = blockIdx.y, q0 = blockIdx.x * 64;
  const int tid = threadIdx.x;
  const int w = tid >> 6, lane = tid & 63, l15 = lane & 15, quad = lane >> 4;

  __shared__ unsigned short Qbf[64][136];  // 17.4 KB
  __shared__ unsigned short Kbf[64][136];  // 17.4 KB
  __shared__ unsigned short Es[64][72];    //  9.2 KB  [q][k], 144B rows
  __shared__ unsigned short Wt[128][72];   // 18.4 KB  [d][k^swz]
  __shared__ float Li[SS];                 //  8.0 KB

  const float* Qb = Q + (size_t)b * SS * DQ;
  const float* Kb = K + (size_t)b * SS * DQ;
  const float* Vb = V + (size_t)b * SS * DQ;
  const int*   Mb = M + (size_t)b * SS * SS;

  // preload replicated Linv strip from own territory (before any O write)
  {
    const float* src = O + ((size_t)b * SS + q0) * DQ;
#pragma unroll
    for (int r = 0; r < 2; ++r) {
      int idx = (tid + r * 256) * 4;
      *(float4*)&Li[idx] = *(const float4*)(src + idx);
    }
  }
  // stage Q tile 64 x 128 -> bf16 (resident)
#pragma unroll
  for (int r = 0; r < 8; ++r) {
    int idx = tid + r * 256;
    int row = idx >> 5, c4 = (idx & 31) * 4;
    float4 v = *(const float4*)(Qb + (size_t)(q0 + row) * DQ + c4);
    *(ushort4*)&Qbf[row][c4] = make_ushort4(f2bf(v.x), f2bf(v.y), f2bf(v.z), f2bf(v.w));
  }
  __syncthreads();

  floatx4 accO[8];
#pragma unroll
  for (int j = 0; j < 8; ++j) accO[j] = (floatx4){0.f, 0.f, 0.f, 0.f};

  const int* mrow = Mb + (size_t)(q0 + 16 * w + l15) * SS;  // this lane's q-row

  for (int k0 = 0; k0 < SS; k0 += 64) {
    // prefetch mask (int4, contiguous k)
    int4 mv[4];
#pragma unroll
    for (int j = 0; j < 4; ++j)
      mv[j] = *(const int4*)(mrow + k0 + 16 * j + quad * 4);
    __syncthreads();  // previous iteration's Kbf/Wt/Es readers done

    // stage K tile 64 x 128 -> bf16
#pragma unroll
    for (int r = 0; r < 8; ++r) {
      int idx = tid + r * 256;
      int row = idx >> 5, c4 = (idx & 31) * 4;
      float4 v = *(const float4*)(Kb + (size_t)(k0 + row) * DQ + c4);
      *(ushort4*)&Kbf[row][c4] = make_ushort4(f2bf(v.x), f2bf(v.y), f2bf(v.z), f2bf(v.w));
    }
    // stage V^T (xor-swizzled cols, ushort2-packed pair writes)
#pragma unroll
    for (int r = 0; r < 4; ++r) {
      int idx = tid + r * 256;          // 0..1023
      int k2  = (idx >> 5) * 2;         // 0,2,...,62
      int c4  = (idx & 31) * 4;
      float4 va = *(const float4*)(Vb + (size_t)(k0 + k2) * DQ + c4);
      float4 vb = *(const float4*)(Vb + (size_t)(k0 + k2 + 1) * DQ + c4);
      float fa[4] = {va.x, va.y, va.z, va.w};
      float fb[4] = {vb.x, vb.y, vb.z, vb.w};
#pragma unroll
      for (int i = 0; i < 4; ++i) {
        int d  = c4 + i;
        int kk = k2 ^ ((((unsigned)d >> 2) & 7) << 3);   // xor on k-bits 3..5
        *(ushort2*)&Wt[d][kk] = make_ushort2(f2bf(fa[i]), f2bf(fb[i]));
      }
    }
    __syncthreads();

    // QK: acc[j] for k-tiles j; C row = k_local, col = q
    floatx4 acc[4];
#pragma unroll
    for (int j = 0; j < 4; ++j) acc[j] = (floatx4){0.f, 0.f, 0.f, 0.f};
#pragma unroll
    for (int d0 = 0; d0 < DQ; d0 += 32) {
      bf16x8 bq = ld_frag(&Qbf[16 * w + l15][d0 + quad * 8]);
#pragma unroll
      for (int j = 0; j < 4; ++j) {
        bf16x8 ak = ld_frag(&Kbf[16 * j + l15][d0 + quad * 8]);
        acc[j] = mfma16(ak, bq, acc[j]);
      }
    }
    // epilogue: k = k0+16j+quad*4+r, q = q0+16w+l15; fold Linv; store Es[q][k]
#pragma unroll
    for (int j = 0; j < 4; ++j) {
      float4 liv = *(const float4*)&Li[k0 + 16 * j + quad * 4];
      float lv[4] = {liv.x, liv.y, liv.z, liv.w};
      int mm[4] = {mv[j].x, mv[j].y, mv[j].z, mv[j].w};
      unsigned short es[4];
#pragma unroll
      for (int r = 0; r < 4; ++r) {
        float s = mm[r] ? 1e-9f : acc[j][r] * SCALE;
        es[r] = f2bf(__expf(s) * lv[r]);
      }
      *(ushort4*)&Es[16 * w + l15][16 * j + quad * 4] =
          make_ushort4(es[0], es[1], es[2], es[3]);
    }
    __syncthreads();

    // PV: A = Wt (8 d-tiles), B = Es (wave's 16 q)
#pragma unroll
    for (int c = 0; c < 2; ++c) {
      bf16x8 be = ld_frag(&Es[16 * w + l15][32 * c + quad * 8]);
#pragma unroll
      for (int j = 0; j < 8; ++j) {
        int d  = 16 * j + l15;
        int kk = (32 * c + quad * 8) ^ ((((unsigned)d >> 2) & 7) << 3);
        bf16x8 aw = ld_frag(&Wt[d][kk]);
        accO[j] = mfma16(aw, be, accO[j]);
      }
    }
  }

  // write O: C row = d = 16j+quad*4+r, col = q = q0+16w+l15 -> float4 stores
#pragma unroll
  for (int j = 0; j < 8; ++j) {
    float* op = O + ((size_t)b * SS + q0 + 16 * w + l15) * DQ + 16 * j + quad * 4;
    *(float4*)op = make_float4(accO[j][0], accO[j][1], accO[j][2], accO[j][3]);
  }
}

// ---------------------------------------------------------------------------
extern "C" void kernel_launch(void* const* d_in, const int* in_sizes, int n_in,
                              void* d_out, int out_size, void* d_ws, size_t ws_size,
                              hipStream_t stream) {
  const float* Q = (const float*)d_in[0];
  const float* K = (const float*)d_in[1];
  const float* V = (const float*)d_in[2];
  const int*   M = (const int*)d_in[3];
  float* O = (float*)d_out;
  (void)d_ws; (void)ws_size;   // d_ws unused: ws_size unverified (R0 post-mortem)

  zero_accum<<<dim3(NB), 256, 0, stream>>>(O);
  pass1_colsum<<<dim3(32, NB, 4), 256, 0, stream>>>(Q, K, M, O);
  combine_linv<<<dim3(NB, 8), 256, 0, stream>>>(O);
  pass2_out<<<dim3(32, NB), 256, 0, stream>>>(Q, K, V, M, O);
}

// Round 5
// 576.819 us; speedup vs baseline: 1.9457x; 1.0294x over previous
//
#include <hip/hip_runtime.h>
#include <math.h>

#define NB 16
#define SS 2048
#define DQ 128
#define SCALE 0.08838834764831845f  // 1/sqrt(128)

typedef __bf16 bf16x8 __attribute__((ext_vector_type(8)));
typedef unsigned short ushort8_t __attribute__((ext_vector_type(8)));
typedef float floatx4 __attribute__((ext_vector_type(4)));

// fp32 -> bf16 round-to-nearest-even (finite randn inputs; no NaN path)
__device__ __forceinline__ unsigned short f2bf(float x) {
  unsigned int u = __float_as_uint(x);
  u += 0x7fffu + ((u >> 16) & 1u);
  return (unsigned short)(u >> 16);
}
union FragU { ushort8_t u; bf16x8 b; };
__device__ __forceinline__ bf16x8 ld_frag(const unsigned short* p) {
  FragU t; t.u = *(const ushort8_t*)p; return t.b;
}
__device__ __forceinline__ floatx4 mfma16(bf16x8 a, bf16x8 b, floatx4 c) {
  return __builtin_amdgcn_mfma_f32_16x16x32_bf16(a, b, c, 0, 0, 0);
}

// d_out scratch layout per batch b (each row = DQ floats):
//   rows q0..q0+15 for q0 in {0,64,...}: replicated Linv strips (2048 floats)
//   rows 16..31: colsum accumulator (2048 floats)  [disjoint from strips]
// All overwritten by pass2's final output.

// ---------------------------------------------------------------------------
__global__ void zero_accum(float* __restrict__ O) {
  float* p = O + (size_t)blockIdx.x * SS * DQ + 16 * DQ;
#pragma unroll
  for (int i = 0; i < 8; ++i) p[threadIdx.x + 256 * i] = 0.f;
}

// ---------------------------------------------------------------------------
// Pass 1: partial colsum[b][k] += sum_{q in chunk} exp(masked_score)
// grid (32 ktiles, NB, 4 qchunks) = 2048 blocks, 256 thr, 4 blocks/CU.
// A=K (64 k), B=Q (16 q per wave): C rows = k -> int4 mask loads.
// Mask loads issued AFTER staging stores, BEFORE barrier -> one drain window.
// ---------------------------------------------------------------------------
__global__ __launch_bounds__(256, 4) void pass1_colsum(
    const float* __restrict__ Q, const float* __restrict__ K,
    const int* __restrict__ M, float* __restrict__ O)
{
  const int k0  = blockIdx.x * 64;
  const int b   = blockIdx.y;
  const int qc  = blockIdx.z;
  const int tid = threadIdx.x;
  const int w = tid >> 6, lane = tid & 63, l15 = lane & 15, quad = lane >> 4;

  __shared__ unsigned short Kbf[64][136];   // 17.4 KB (resident)
  __shared__ unsigned short Qbf[64][136];   // 17.4 KB (per q-iter)
  __shared__ float red[4][64];

  const float* Qb = Q + (size_t)b * SS * DQ;
  const float* Kb = K + (size_t)b * SS * DQ;
  const int*   Mb = M + (size_t)b * SS * SS;

  // stage K strip 64 x 128 -> bf16 (resident)
#pragma unroll
  for (int r = 0; r < 8; ++r) {
    int idx = tid + r * 256;
    int row = idx >> 5, c4 = (idx & 31) * 4;
    float4 v = *(const float4*)(Kb + (size_t)(k0 + row) * DQ + c4);
    *(ushort4*)&Kbf[row][c4] = make_ushort4(f2bf(v.x), f2bf(v.y), f2bf(v.z), f2bf(v.w));
  }

  float colacc[16];
#pragma unroll
  for (int t = 0; t < 16; ++t) colacc[t] = 0.f;

  const int qlane = 16 * w + l15;     // wave-local q row within iter tile

  for (int qi = 0; qi < 8; ++qi) {
    const int q0 = qc * 512 + qi * 64;
    __syncthreads();  // Qbf readers of prev iter done (1st: after K staging)
    // stage Q tile 64 x 128 -> bf16
#pragma unroll
    for (int r = 0; r < 8; ++r) {
      int idx = tid + r * 256;
      int row = idx >> 5, c4 = (idx & 31) * 4;
      float4 v = *(const float4*)(Qb + (size_t)(q0 + row) * DQ + c4);
      *(ushort4*)&Qbf[row][c4] = make_ushort4(f2bf(v.x), f2bf(v.y), f2bf(v.z), f2bf(v.w));
    }
    // mask prefetch: issued here so it drains at the SAME barrier as staging
    int4 mv[4];
#pragma unroll
    for (int i = 0; i < 4; ++i)
      mv[i] = *(const int4*)(Mb + (size_t)(q0 + qlane) * SS + k0 + 16 * i + quad * 4);
    __syncthreads();

    floatx4 acc[4];
#pragma unroll
    for (int i = 0; i < 4; ++i) acc[i] = (floatx4){0.f, 0.f, 0.f, 0.f};
#pragma unroll
    for (int d0 = 0; d0 < DQ; d0 += 32) {
      bf16x8 bq = ld_frag(&Qbf[qlane][d0 + quad * 8]);
#pragma unroll
      for (int i = 0; i < 4; ++i) {
        bf16x8 ak = ld_frag(&Kbf[16 * i + l15][d0 + quad * 8]);
        acc[i] = mfma16(ak, bq, acc[i]);
      }
    }
    // epilogue: C row = k_local = 16i+quad*4+r, col = q = q0+16w+l15
#pragma unroll
    for (int i = 0; i < 4; ++i) {
      int mm[4] = {mv[i].x, mv[i].y, mv[i].z, mv[i].w};
#pragma unroll
      for (int r = 0; r < 4; ++r) {
        float s = mm[r] ? 1e-9f : acc[i][r] * SCALE;
        colacc[i * 4 + r] += __expf(s);
      }
    }
  }

  // reduce over the 16 q-lanes (l15 dimension)
#pragma unroll
  for (int t = 0; t < 16; ++t) {
    colacc[t] += __shfl_xor(colacc[t], 1, 64);
    colacc[t] += __shfl_xor(colacc[t], 2, 64);
    colacc[t] += __shfl_xor(colacc[t], 4, 64);
    colacc[t] += __shfl_xor(colacc[t], 8, 64);
  }
  if (l15 == 0) {
#pragma unroll
    for (int i = 0; i < 4; ++i)
#pragma unroll
      for (int r = 0; r < 4; ++r)
        red[w][16 * i + quad * 4 + r] = colacc[i * 4 + r];
  }
  __syncthreads();
  if (tid < 64) {
    float s = red[0][tid] + red[1][tid] + red[2][tid] + red[3][tid];
    atomicAdd(O + (size_t)b * SS * DQ + 16 * DQ + k0 + tid, s);
  }
}

// ---------------------------------------------------------------------------
// Combine: inv = 1/colsum; write replicated strips. grid (NB, 8), 256 thr.
// ---------------------------------------------------------------------------
__global__ void combine_linv(float* __restrict__ O) {
  const int b  = blockIdx.x;
  const int jb = blockIdx.y * 4;
  float* Ob = O + (size_t)b * SS * DQ;
#pragma unroll
  for (int it = 0; it < 8; ++it) {
    int k = threadIdx.x + 256 * it;
    float inv = 1.0f / Ob[16 * DQ + k];
#pragma unroll
    for (int j = 0; j < 4; ++j)
      Ob[(size_t)(64 * (jb + j)) * DQ + k] = inv;
  }
}

// ---------------------------------------------------------------------------
// Pass 2: O[q][d] = sum_k exp(masked_score)*Linv[k]*V[k][d]
// grid (32, NB), 256 thr, 3 blocks/CU (53 KB LDS). Q fragments in REGISTERS
// (each wave owns its 16 q rows). Es rows are wave-private -> NO barrier
// between QK-epilogue and PV (lgkmcnt ordering suffices). 2 barriers/iter.
// ---------------------------------------------------------------------------
__global__ __launch_bounds__(256, 3) void pass2_out(
    const float* __restrict__ Q, const float* __restrict__ K,
    const float* __restrict__ V, const int* __restrict__ M,
    float* __restrict__ O)
{
  const int b = blockIdx.y, q0 = blockIdx.x * 64;
  const int tid = threadIdx.x;
  const int w = tid >> 6, lane = tid & 63, l15 = lane & 15, quad = lane >> 4;

  __shared__ unsigned short Kbf[64][136];  // 17.4 KB
  __shared__ unsigned short Es[64][72];    //  9.2 KB  [q][k], wave-private rows
  __shared__ unsigned short Wt[128][72];   // 18.4 KB  [d][k^swz]
  __shared__ float Li[SS];                 //  8.0 KB

  const float* Qb = Q + (size_t)b * SS * DQ;
  const float* Kb = K + (size_t)b * SS * DQ;
  const float* Vb = V + (size_t)b * SS * DQ;
  const int*   Mb = M + (size_t)b * SS * SS;

  // preload replicated Linv strip from own territory (before any O write)
  {
    const float* src = O + ((size_t)b * SS + q0) * DQ;
#pragma unroll
    for (int r = 0; r < 2; ++r) {
      int idx = (tid + r * 256) * 4;
      *(float4*)&Li[idx] = *(const float4*)(src + idx);
    }
  }
  // Q fragments in registers: this lane's q row, 4 fragments over d
  FragU qf[4];
  {
    const float* qrow = Qb + (size_t)(q0 + 16 * w + l15) * DQ;
#pragma unroll
    for (int i = 0; i < 4; ++i) {
      float4 a = *(const float4*)(qrow + 32 * i + quad * 8);
      float4 c = *(const float4*)(qrow + 32 * i + quad * 8 + 4);
      qf[i].u = (ushort8_t){f2bf(a.x), f2bf(a.y), f2bf(a.z), f2bf(a.w),
                            f2bf(c.x), f2bf(c.y), f2bf(c.z), f2bf(c.w)};
    }
  }

  floatx4 accO[8];
#pragma unroll
  for (int j = 0; j < 8; ++j) accO[j] = (floatx4){0.f, 0.f, 0.f, 0.f};

  const int* mrow = Mb + (size_t)(q0 + 16 * w + l15) * SS;  // this lane's q-row

  for (int k0 = 0; k0 < SS; k0 += 64) {
    __syncthreads();  // prev iter's Kbf/Wt readers done (1st: Li visible after)

    // stage K tile 64 x 128 -> bf16
#pragma unroll
    for (int r = 0; r < 8; ++r) {
      int idx = tid + r * 256;
      int row = idx >> 5, c4 = (idx & 31) * 4;
      float4 v = *(const float4*)(Kb + (size_t)(k0 + row) * DQ + c4);
      *(ushort4*)&Kbf[row][c4] = make_ushort4(f2bf(v.x), f2bf(v.y), f2bf(v.z), f2bf(v.w));
    }
    // stage V^T (xor-swizzled cols, ushort2-packed pair writes)
#pragma unroll
    for (int r = 0; r < 4; ++r) {
      int idx = tid + r * 256;          // 0..1023
      int k2  = (idx >> 5) * 2;         // 0,2,...,62
      int c4  = (idx & 31) * 4;
      float4 va = *(const float4*)(Vb + (size_t)(k0 + k2) * DQ + c4);
      float4 vb = *(const float4*)(Vb + (size_t)(k0 + k2 + 1) * DQ + c4);
      float fa[4] = {va.x, va.y, va.z, va.w};
      float fb[4] = {vb.x, vb.y, vb.z, vb.w};
#pragma unroll
      for (int i = 0; i < 4; ++i) {
        int d  = c4 + i;
        int kk = k2 ^ ((((unsigned)d >> 2) & 7) << 3);   // xor on k-bits 3..5
        *(ushort2*)&Wt[d][kk] = make_ushort2(f2bf(fa[i]), f2bf(fb[i]));
      }
    }
    // mask prefetch: same drain window as staging loads
    int4 mv[4];
#pragma unroll
    for (int j = 0; j < 4; ++j)
      mv[j] = *(const int4*)(mrow + k0 + 16 * j + quad * 4);
    __syncthreads();

    // QK: C row = k_local = 16j+quad*4+r, col = q = q0+16w+l15
    floatx4 acc[4];
#pragma unroll
    for (int j = 0; j < 4; ++j) acc[j] = (floatx4){0.f, 0.f, 0.f, 0.f};
#pragma unroll
    for (int i = 0; i < 4; ++i) {
      bf16x8 bq = qf[i].b;
#pragma unroll
      for (int j = 0; j < 4; ++j) {
        bf16x8 ak = ld_frag(&Kbf[16 * j + l15][32 * i + quad * 8]);
        acc[j] = mfma16(ak, bq, acc[j]);
      }
    }
    // epilogue: mask+exp, fold Linv, write Es (own wave's rows only)
#pragma unroll
    for (int j = 0; j < 4; ++j) {
      float4 liv = *(const float4*)&Li[k0 + 16 * j + quad * 4];
      float lv[4] = {liv.x, liv.y, liv.z, liv.w};
      int mm[4] = {mv[j].x, mv[j].y, mv[j].z, mv[j].w};
      unsigned short es[4];
#pragma unroll
      for (int r = 0; r < 4; ++r) {
        float s = mm[r] ? 1e-9f : acc[j][r] * SCALE;
        es[r] = f2bf(__expf(s) * lv[r]);
      }
      *(ushort4*)&Es[16 * w + l15][16 * j + quad * 4] =
          make_ushort4(es[0], es[1], es[2], es[3]);
    }
    // PV (no barrier needed: Es rows written & read by the same wave)
#pragma unroll
    for (int c = 0; c < 2; ++c) {
      bf16x8 be = ld_frag(&Es[16 * w + l15][32 * c + quad * 8]);
#pragma unroll
      for (int j = 0; j < 8; ++j) {
        int d  = 16 * j + l15;
        int kk = (32 * c + quad * 8) ^ ((((unsigned)d >> 2) & 7) << 3);
        bf16x8 aw = ld_frag(&Wt[d][kk]);
        accO[j] = mfma16(aw, be, accO[j]);
      }
    }
  }

  // write O: C row = d = 16j+quad*4+r, col = q = q0+16w+l15 -> float4 stores
#pragma unroll
  for (int j = 0; j < 8; ++j) {
    float* op = O + ((size_t)b * SS + q0 + 16 * w + l15) * DQ + 16 * j + quad * 4;
    *(float4*)op = make_float4(accO[j][0], accO[j][1], accO[j][2], accO[j][3]);
  }
}

// ---------------------------------------------------------------------------
extern "C" void kernel_launch(void* const* d_in, const int* in_sizes, int n_in,
                              void* d_out, int out_size, void* d_ws, size_t ws_size,
                              hipStream_t stream) {
  const float* Q = (const float*)d_in[0];
  const float* K = (const float*)d_in[1];
  const float* V = (const float*)d_in[2];
  const int*   M = (const int*)d_in[3];
  float* O = (float*)d_out;
  (void)d_ws; (void)ws_size;   // d_ws unused: ws_size unverified (R0 post-mortem)

  zero_accum<<<dim3(NB), 256, 0, stream>>>(O);
  pass1_colsum<<<dim3(32, NB, 4), 256, 0, stream>>>(Q, K, M, O);
  combine_linv<<<dim3(NB, 8), 256, 0, stream>>>(O);
  pass2_out<<<dim3(32, NB), 256, 0, stream>>>(Q, K, V, M, O);
}

// Round 6
// 517.788 us; speedup vs baseline: 2.1675x; 1.1140x over previous
//
#include <hip/hip_runtime.h>
#include <math.h>

#define NB 16
#define SS 2048
#define DQ 128
#define SCALE 0.08838834764831845f  // 1/sqrt(128)

typedef __bf16 bf16x8 __attribute__((ext_vector_type(8)));
typedef unsigned short ushort8_t __attribute__((ext_vector_type(8)));
typedef float floatx4 __attribute__((ext_vector_type(4)));

// fp32 -> bf16 round-to-nearest-even (finite randn inputs; no NaN path)
__device__ __forceinline__ unsigned short f2bf(float x) {
  unsigned int u = __float_as_uint(x);
  u += 0x7fffu + ((u >> 16) & 1u);
  return (unsigned short)(u >> 16);
}
union FragU { ushort8_t u; bf16x8 b; };
__device__ __forceinline__ bf16x8 ld_frag(const unsigned short* p) {
  FragU t; t.u = *(const ushort8_t*)p; return t.b;
}
__device__ __forceinline__ floatx4 mfma16(bf16x8 a, bf16x8 b, floatx4 c) {
  return __builtin_amdgcn_mfma_f32_16x16x32_bf16(a, b, c, 0, 0, 0);
}

// LDS-only barrier: waits DS ops, leaves global loads (vmcnt) IN FLIGHT.
// __syncthreads() would emit s_waitcnt vmcnt(0) and drain the prefetch.
__device__ __forceinline__ void bar_lds() {
  asm volatile("s_waitcnt lgkmcnt(0)\n\ts_barrier" ::: "memory");
}

// d_out scratch layout per batch b (each row = DQ floats):
//   rows q0..q0+15 for q0 in {0,64,...}: replicated Linv strips (2048 floats)
//   rows 16..31: colsum accumulator (2048 floats)  [disjoint from strips]
// All overwritten by pass2's final output.

// ---------------------------------------------------------------------------
__global__ void zero_accum(float* __restrict__ O) {
  float* p = O + (size_t)blockIdx.x * SS * DQ + 16 * DQ;
#pragma unroll
  for (int i = 0; i < 8; ++i) p[threadIdx.x + 256 * i] = 0.f;
}

// ---------------------------------------------------------------------------
// Pass 1: partial colsum[b][k] += sum_{q in chunk} exp(masked_score)
// grid (32 ktiles, NB, 4 qchunks) = 2048 blocks, 256 thr, 4 blocks/CU.
// Register-prefetched Q tile + mask, LDS-only barriers: next tile's global
// loads stay in flight across the whole current iteration.
// ---------------------------------------------------------------------------
__global__ __launch_bounds__(256, 4) void pass1_colsum(
    const float* __restrict__ Q, const float* __restrict__ K,
    const int* __restrict__ M, float* __restrict__ O)
{
  const int k0  = blockIdx.x * 64;
  const int b   = blockIdx.y;
  const int qc  = blockIdx.z;
  const int tid = threadIdx.x;
  const int w = tid >> 6, lane = tid & 63, l15 = lane & 15, quad = lane >> 4;

  __shared__ unsigned short Kbf[64][136];   // 17.4 KB (resident)
  __shared__ unsigned short Qbf[64][136];   // 17.4 KB (per q-iter)
  __shared__ float red[4][64];

  const float* Qb = Q + (size_t)b * SS * DQ;
  const float* Kb = K + (size_t)b * SS * DQ;
  const int*   Mb = M + (size_t)b * SS * SS;

  const int srow = tid >> 5;              // staging row base (this thread)
  const int sc4  = (tid & 31) * 4;        // staging col (floats)

  // stage K strip 64 x 128 -> bf16 (resident)
#pragma unroll
  for (int r = 0; r < 8; ++r) {
    int row = srow + r * 8;
    float4 v = *(const float4*)(Kb + (size_t)(k0 + row) * DQ + sc4);
    *(ushort4*)&Kbf[row][sc4] = make_ushort4(f2bf(v.x), f2bf(v.y), f2bf(v.z), f2bf(v.w));
  }

  const int qlane = 16 * w + l15;         // wave-local q row within iter tile

  // prologue: prefetch q-tile 0 + its mask into registers
  float4 qreg[8];
  int4 mv_nxt[4];
  {
    const int q0 = qc * 512;
#pragma unroll
    for (int r = 0; r < 8; ++r)
      qreg[r] = *(const float4*)(Qb + (size_t)(q0 + srow + r * 8) * DQ + sc4);
#pragma unroll
    for (int i = 0; i < 4; ++i)
      mv_nxt[i] = *(const int4*)(Mb + (size_t)(q0 + qlane) * SS + k0 + 16 * i + quad * 4);
  }

  float colacc[16];
#pragma unroll
  for (int t = 0; t < 16; ++t) colacc[t] = 0.f;

  for (int qi = 0; qi < 8; ++qi) {
    bar_lds();  // prev Qbf readers done (1st iter: K-staging ds_writes drained)
    int4 mv[4] = {mv_nxt[0], mv_nxt[1], mv_nxt[2], mv_nxt[3]};
    // store prefetched Q regs -> LDS (vmcnt waits are fine-grained here)
#pragma unroll
    for (int r = 0; r < 8; ++r) {
      float4 v = qreg[r];
      *(ushort4*)&Qbf[srow + r * 8][sc4] =
          make_ushort4(f2bf(v.x), f2bf(v.y), f2bf(v.z), f2bf(v.w));
    }
    bar_lds();  // Qbf ready; prefetch below flies across the next barrier
    if (qi < 7) {
      const int qn = qc * 512 + (qi + 1) * 64;
#pragma unroll
      for (int r = 0; r < 8; ++r)
        qreg[r] = *(const float4*)(Qb + (size_t)(qn + srow + r * 8) * DQ + sc4);
#pragma unroll
      for (int i = 0; i < 4; ++i)
        mv_nxt[i] = *(const int4*)(Mb + (size_t)(qn + qlane) * SS + k0 + 16 * i + quad * 4);
    }

    floatx4 acc[4];
#pragma unroll
    for (int i = 0; i < 4; ++i) acc[i] = (floatx4){0.f, 0.f, 0.f, 0.f};
#pragma unroll
    for (int d0 = 0; d0 < DQ; d0 += 32) {
      bf16x8 bq = ld_frag(&Qbf[qlane][d0 + quad * 8]);
#pragma unroll
      for (int i = 0; i < 4; ++i) {
        bf16x8 ak = ld_frag(&Kbf[16 * i + l15][d0 + quad * 8]);
        acc[i] = mfma16(ak, bq, acc[i]);
      }
    }
    // epilogue: C row = k_local = 16i+quad*4+r, col = q = qlane
#pragma unroll
    for (int i = 0; i < 4; ++i) {
      int mm[4] = {mv[i].x, mv[i].y, mv[i].z, mv[i].w};
#pragma unroll
      for (int r = 0; r < 4; ++r) {
        float s = mm[r] ? 1e-9f : acc[i][r] * SCALE;
        colacc[i * 4 + r] += __expf(s);
      }
    }
  }

  // reduce over the 16 q-lanes (l15 dimension)
#pragma unroll
  for (int t = 0; t < 16; ++t) {
    colacc[t] += __shfl_xor(colacc[t], 1, 64);
    colacc[t] += __shfl_xor(colacc[t], 2, 64);
    colacc[t] += __shfl_xor(colacc[t], 4, 64);
    colacc[t] += __shfl_xor(colacc[t], 8, 64);
  }
  if (l15 == 0) {
#pragma unroll
    for (int i = 0; i < 4; ++i)
#pragma unroll
      for (int r = 0; r < 4; ++r)
        red[w][16 * i + quad * 4 + r] = colacc[i * 4 + r];
  }
  bar_lds();
  if (tid < 64) {
    float s = red[0][tid] + red[1][tid] + red[2][tid] + red[3][tid];
    atomicAdd(O + (size_t)b * SS * DQ + 16 * DQ + k0 + tid, s);
  }
}

// ---------------------------------------------------------------------------
// Combine: inv = 1/colsum; write replicated strips. grid (NB, 8), 256 thr.
// ---------------------------------------------------------------------------
__global__ void combine_linv(float* __restrict__ O) {
  const int b  = blockIdx.x;
  const int jb = blockIdx.y * 4;
  float* Ob = O + (size_t)b * SS * DQ;
#pragma unroll
  for (int it = 0; it < 8; ++it) {
    int k = threadIdx.x + 256 * it;
    float inv = 1.0f / Ob[16 * DQ + k];
#pragma unroll
    for (int j = 0; j < 4; ++j)
      Ob[(size_t)(64 * (jb + j)) * DQ + k] = inv;
  }
}

// ---------------------------------------------------------------------------
// Pass 2: O[q][d] = sum_k exp(masked_score)*Linv[k]*V[k][d]
// grid (32, NB) = 512 blocks (2/CU), 256 thr. Q in registers; Es rows
// wave-private (no barrier before PV). K/V/mask register-prefetched one
// k-tile ahead; LDS-only barriers keep the prefetch in flight.
// ---------------------------------------------------------------------------
__global__ __launch_bounds__(256, 2) void pass2_out(
    const float* __restrict__ Q, const float* __restrict__ K,
    const float* __restrict__ V, const int* __restrict__ M,
    float* __restrict__ O)
{
  const int b = blockIdx.y, q0 = blockIdx.x * 64;
  const int tid = threadIdx.x;
  const int w = tid >> 6, lane = tid & 63, l15 = lane & 15, quad = lane >> 4;

  __shared__ unsigned short Kbf[64][136];  // 17.4 KB
  __shared__ unsigned short Es[64][72];    //  9.2 KB  [q][k], wave-private rows
  __shared__ unsigned short Wt[128][72];   // 18.4 KB  [d][k^swz]
  __shared__ float Li[SS];                 //  8.0 KB

  const float* Qb = Q + (size_t)b * SS * DQ;
  const float* Kb = K + (size_t)b * SS * DQ;
  const float* Vb = V + (size_t)b * SS * DQ;
  const int*   Mb = M + (size_t)b * SS * SS;

  const int srow = tid >> 5;
  const int sc4  = (tid & 31) * 4;

  // preload replicated Linv strip from own territory (before any O write)
  {
    const float* src = O + ((size_t)b * SS + q0) * DQ;
#pragma unroll
    for (int r = 0; r < 2; ++r) {
      int idx = (tid + r * 256) * 4;
      *(float4*)&Li[idx] = *(const float4*)(src + idx);
    }
  }
  // Q fragments in registers: this lane's q row, 4 fragments over d
  FragU qf[4];
  {
    const float* qrow = Qb + (size_t)(q0 + 16 * w + l15) * DQ;
#pragma unroll
    for (int i = 0; i < 4; ++i) {
      float4 a = *(const float4*)(qrow + 32 * i + quad * 8);
      float4 c = *(const float4*)(qrow + 32 * i + quad * 8 + 4);
      qf[i].u = (ushort8_t){f2bf(a.x), f2bf(a.y), f2bf(a.z), f2bf(a.w),
                            f2bf(c.x), f2bf(c.y), f2bf(c.z), f2bf(c.w)};
    }
  }

  floatx4 accO[8];
#pragma unroll
  for (int j = 0; j < 8; ++j) accO[j] = (floatx4){0.f, 0.f, 0.f, 0.f};

  const int* mrow = Mb + (size_t)(q0 + 16 * w + l15) * SS;  // this lane's q-row

  // prologue: prefetch k-tile 0 (K rows, V row-pairs, mask) into registers
  float4 kreg[8], vreg[8];
  int4 mv_nxt[4];
  const int vk2 = (tid >> 5) * 2;   // V row-pair base for this thread (0..14)
  {
#pragma unroll
    for (int r = 0; r < 8; ++r)
      kreg[r] = *(const float4*)(Kb + (size_t)(srow + r * 8) * DQ + sc4);
#pragma unroll
    for (int r = 0; r < 4; ++r) {
      int k2 = vk2 + r * 16;
      vreg[2 * r]     = *(const float4*)(Vb + (size_t)(k2)     * DQ + sc4);
      vreg[2 * r + 1] = *(const float4*)(Vb + (size_t)(k2 + 1) * DQ + sc4);
    }
#pragma unroll
    for (int j = 0; j < 4; ++j)
      mv_nxt[j] = *(const int4*)(mrow + 16 * j + quad * 4);
  }

  for (int k0 = 0; k0 < SS; k0 += 64) {
    bar_lds();  // prev iter's Kbf/Wt readers done; Li/initial ds_writes drained
    int4 mv[4] = {mv_nxt[0], mv_nxt[1], mv_nxt[2], mv_nxt[3]};

    // store prefetched K -> Kbf (bf16)
#pragma unroll
    for (int r = 0; r < 8; ++r) {
      float4 v = kreg[r];
      *(ushort4*)&Kbf[srow + r * 8][sc4] =
          make_ushort4(f2bf(v.x), f2bf(v.y), f2bf(v.z), f2bf(v.w));
    }
    // store prefetched V -> Wt (transposed, xor-swizzled, ushort2 pairs)
#pragma unroll
    for (int r = 0; r < 4; ++r) {
      int k2 = vk2 + r * 16;
      float fa[4] = {vreg[2*r].x, vreg[2*r].y, vreg[2*r].z, vreg[2*r].w};
      float fb[4] = {vreg[2*r+1].x, vreg[2*r+1].y, vreg[2*r+1].z, vreg[2*r+1].w};
#pragma unroll
      for (int i = 0; i < 4; ++i) {
        int d  = sc4 + i;
        int kk = k2 ^ ((((unsigned)d >> 2) & 7) << 3);   // xor on k-bits 3..5
        *(ushort2*)&Wt[d][kk] = make_ushort2(f2bf(fa[i]), f2bf(fb[i]));
      }
    }
    bar_lds();  // LDS ready; the prefetch below stays in flight across iters

    if (k0 + 64 < SS) {
      const int kn = k0 + 64;
#pragma unroll
      for (int r = 0; r < 8; ++r)
        kreg[r] = *(const float4*)(Kb + (size_t)(kn + srow + r * 8) * DQ + sc4);
#pragma unroll
      for (int r = 0; r < 4; ++r) {
        int k2 = vk2 + r * 16;
        vreg[2 * r]     = *(const float4*)(Vb + (size_t)(kn + k2)     * DQ + sc4);
        vreg[2 * r + 1] = *(const float4*)(Vb + (size_t)(kn + k2 + 1) * DQ + sc4);
      }
#pragma unroll
      for (int j = 0; j < 4; ++j)
        mv_nxt[j] = *(const int4*)(mrow + kn + 16 * j + quad * 4);
    }

    // QK: C row = k_local = 16j+quad*4+r, col = q = q0+16w+l15
    floatx4 acc[4];
#pragma unroll
    for (int j = 0; j < 4; ++j) acc[j] = (floatx4){0.f, 0.f, 0.f, 0.f};
#pragma unroll
    for (int i = 0; i < 4; ++i) {
      bf16x8 bq = qf[i].b;
#pragma unroll
      for (int j = 0; j < 4; ++j) {
        bf16x8 ak = ld_frag(&Kbf[16 * j + l15][32 * i + quad * 8]);
        acc[j] = mfma16(ak, bq, acc[j]);
      }
    }
    // epilogue: mask+exp, fold Linv, write Es (own wave's rows only)
#pragma unroll
    for (int j = 0; j < 4; ++j) {
      float4 liv = *(const float4*)&Li[k0 + 16 * j + quad * 4];
      float lv[4] = {liv.x, liv.y, liv.z, liv.w};
      int mm[4] = {mv[j].x, mv[j].y, mv[j].z, mv[j].w};
      unsigned short es[4];
#pragma unroll
      for (int r = 0; r < 4; ++r) {
        float s = mm[r] ? 1e-9f : acc[j][r] * SCALE;
        es[r] = f2bf(__expf(s) * lv[r]);
      }
      *(ushort4*)&Es[16 * w + l15][16 * j + quad * 4] =
          make_ushort4(es[0], es[1], es[2], es[3]);
    }
    // PV (no barrier: Es rows written & read by the same wave; lgkm ordering)
#pragma unroll
    for (int c = 0; c < 2; ++c) {
      bf16x8 be = ld_frag(&Es[16 * w + l15][32 * c + quad * 8]);
#pragma unroll
      for (int j = 0; j < 8; ++j) {
        int d  = 16 * j + l15;
        int kk = (32 * c + quad * 8) ^ ((((unsigned)d >> 2) & 7) << 3);
        bf16x8 aw = ld_frag(&Wt[d][kk]);
        accO[j] = mfma16(aw, be, accO[j]);
      }
    }
  }

  // write O: C row = d = 16j+quad*4+r, col = q = q0+16w+l15 -> float4 stores
#pragma unroll
  for (int j = 0; j < 8; ++j) {
    float* op = O + ((size_t)b * SS + q0 + 16 * w + l15) * DQ + 16 * j + quad * 4;
    *(float4*)op = make_float4(accO[j][0], accO[j][1], accO[j][2], accO[j][3]);
  }
}

// ---------------------------------------------------------------------------
extern "C" void kernel_launch(void* const* d_in, const int* in_sizes, int n_in,
                              void* d_out, int out_size, void* d_ws, size_t ws_size,
                              hipStream_t stream) {
  const float* Q = (const float*)d_in[0];
  const float* K = (const float*)d_in[1];
  const float* V = (const float*)d_in[2];
  const int*   M = (const int*)d_in[3];
  float* O = (float*)d_out;
  (void)d_ws; (void)ws_size;   // d_ws unused: ws_size unverified (R0 post-mortem)

  zero_accum<<<dim3(NB), 256, 0, stream>>>(O);
  pass1_colsum<<<dim3(32, NB, 4), 256, 0, stream>>>(Q, K, M, O);
  combine_linv<<<dim3(NB, 8), 256, 0, stream>>>(O);
  pass2_out<<<dim3(32, NB), 256, 0, stream>>>(Q, K, V, M, O);
}